// Round 16
// baseline (16.528 us; speedup 1.0000x reference)
//
#include <hip/hip_runtime.h>
#include <math.h>

// sin(3e-5 * pi/10): proven in r15 (absmax unchanged vs the 3e-4 rounds).
#define THR_BASE 9.42477e-6f
#define KFOLD 256.0f          // count-fold constant: acc += mag + KFOLD
#define KFOLD_INV 0.00390625f // 1/256
#define LSTRIDE 532           // dwords/LDS row (16B-aligned rows)

typedef float v2f __attribute__((ext_vector_type(2)));

// x: (16,1,512,512) f32 ; out: (16,10,64,64) f32
// Block (512 thr) = one cell-row (ch, n uniform). 8 threads/cell, 1 pixel
// row (8 px) each -> 8192 waves = 8 waves/SIMD (occupancy restore).
// LDS-staged zero-padded rows; cumulative-threshold pk-binning (r15-proven).
__global__ void __launch_bounds__(512, 6) hog_kernel(const float* __restrict__ x,
                                                     float* __restrict__ out) {
    __shared__ float s[10 * LSTRIDE];

    int tid = threadIdx.x;
    int blk = blockIdx.x;
    int ch  = blk & 63;          // block-uniform cell-row
    int n   = blk >> 6;          // block-uniform image
    const float* img = x + (size_t)n * (512 * 512);
    int R0 = ch * 8 - 1;         // first staged image row

    // ---- Stage: 10 rows x 512 cols = 1280 float4, coalesced (512 threads).
    for (int j = tid; j < 1280; j += 512) {
        int lrow = j >> 7;               // 128 float4 per row
        int cb = j & 127;                // float4 index within row
        int R = R0 + lrow;
        bool rok = (R >= 0) && (R < 512);
        const float4* gp = (const float4*)(img + (size_t)(rok ? R : 0) * 512) + cb;
        float4 v = *gp;
        float m = rok ? 1.0f : 0.0f;     // zero out-of-range rows
        int L = lrow * LSTRIDE + 5 + cb * 4;
        s[L + 0] = v.x * m;
        s[L + 1] = v.y * m;
        s[L + 2] = v.z * m;
        s[L + 3] = v.w * m;
    }
    if (tid < 10) {                       // zero pads: img col -1 and 512
        s[tid * LSTRIDE + 4]   = 0.0f;
        s[tid * LSTRIDE + 517] = 0.0f;
    }
    __syncthreads();

    int r    = tid & 7;          // pixel row within cell
    int cw   = tid >> 3;         // cell within the block's row (0..63)
    int row  = ch * 8 + r;       // this thread's pixel row
    int col0 = cw * 8;

    // ---- Halo read from LDS: 3 rows x 10 cols, branch-free, zero-padded.
    // Image row (row-1+d) is local row r+d; L(col0-1) = 8*cw+4.
    float t0[10], t1[10], t2[10];
    {
        int base = r * LSTRIDE + 8 * cw + 4;
#define READROW(DST, D)                                                   \
        {                                                                 \
            const float* rp = &s[base + (D) * LSTRIDE];                   \
            float4 a4 = *(const float4*)(rp);                             \
            float4 b4 = *(const float4*)(rp + 4);                         \
            DST[0] = a4.x; DST[1] = a4.y; DST[2] = a4.z; DST[3] = a4.w;   \
            DST[4] = b4.x; DST[5] = b4.y; DST[6] = b4.z; DST[7] = b4.w;   \
            DST[8] = rp[8]; DST[9] = rp[9];                               \
        }
        READROW(t0, 0)
        READROW(t1, 1)
        READROW(t2, 2)
#undef READROW
    }

    // ---- dd (col sums) / uu (row diffs) ----
    float dd[10], uu[10];
#pragma unroll
    for (int c = 0; c < 10; ++c) {
        dd[c] = fmaf(2.0f, t1[c], t0[c] + t2[c]);
        uu[c] = t0[c] - t2[c];
    }

    // ---- all 8 gx / gy ----
    float gx[8], gy[8];
#pragma unroll
    for (int c = 0; c < 8; ++c) {
        gx[c] = dd[c] - dd[c + 2];
        gy[c] = fmaf(2.0f, uu[c + 1], uu[c] + uu[c + 2]);
    }

    // ---- hot loop: packed cumulative-threshold accumulate (r15-proven) ----
    v2f acc[5];                     // .x = A side (qq=0), .y = B side (qq=1)
#pragma unroll
    for (int j = 0; j < 5; ++j) acc[j] = (v2f)(0.0f);
    unsigned bmask = 0u;            // boundary-pixel flags (rare), 8 bits

#pragma unroll
    for (int p = 0; p < 8; ++p) {
        float gxc = gx[p], gyc = gy[p];
        float mag = __builtin_amdgcn_sqrtf(fmaf(gxc, gxc, gyc * gyc));
        float a = fabsf(gxc), b = fabsf(gyc);

        // Sector tests: m_k = a*cos(k*pi/10) - b*sin(k*pi/10), k=1..4
        float m1 = fmaf(a, 0.95105651629515353f, -(b * 0.30901699437494740f));
        float m2 = fmaf(a, 0.80901699437494745f, -(b * 0.58778525229247314f));
        float m3 = fmaf(a, 0.58778525229247314f, -(b * 0.80901699437494745f));
        float m4 = fmaf(a, 0.30901699437494740f, -(b * 0.95105651629515353f));

        int k1 = __float_as_int(m1) >> 31;   // all-ones iff m_k < 0
        int k2 = __float_as_int(m2) >> 31;
        int k3 = __float_as_int(m3) >> 31;
        int k4 = __float_as_int(m4) >> 31;
        int qm = (__float_as_int(gxc) ^ __float_as_int(gyc)) >> 31; // qq mask

        int fK = __float_as_int(mag + KFOLD);
        int fA = fK & ~qm;                   // magK on A side, else 0
        int fB = fK & qm;                    // magK on B side, else 0

        v2f v0; v0.x = __int_as_float(fA);      v0.y = __int_as_float(fB);
        v2f v1; v1.x = __int_as_float(fA & ~k1); v1.y = __int_as_float(fB & ~k1);
        v2f v2; v2.x = __int_as_float(fA & ~k2); v2.y = __int_as_float(fB & ~k2);
        v2f v3; v3.x = __int_as_float(fA & ~k3); v3.y = __int_as_float(fB & ~k3);
        v2f v4; v4.x = __int_as_float(fA & ~k4); v4.y = __int_as_float(fB & ~k4);
        acc[0] += v0; acc[1] += v1; acc[2] += v2; acc[3] += v3; acc[4] += v4;

        float dmin = fminf(fminf(fminf(fabsf(m1), fabsf(m2)), fabsf(m3)),
                           fminf(fminf(fabsf(m4), a), b));
        bmask = (dmin < THR_BASE * fmaxf(mag, 1.0f)) ? (bmask | (1u << p)) : bmask;
    }

    // ---- Rare fixup: undo fast contribution, apply exact f64 sector ----
    while (__any((int)(bmask != 0u))) {
        if (bmask) {
            int p = (int)__builtin_ctz(bmask);
            bmask &= bmask - 1u;
            int pc = col0 + p;
            int rm = row - 1, rq = row + 1;
            int cm = pc - 1, cp = pc + 1;
            bool rmok = rm >= 0, rqok = rq < 512;
            bool cmok = cm >= 0, cpok = cp < 512;
            float w00 = (rmok && cmok) ? img[(size_t)rm * 512 + cm] : 0.0f;
            float w01 = rmok ? img[(size_t)rm * 512 + pc] : 0.0f;
            float w02 = (rmok && cpok) ? img[(size_t)rm * 512 + cp] : 0.0f;
            float w10 = cmok ? img[(size_t)row * 512 + cm] : 0.0f;
            float w12 = cpok ? img[(size_t)row * 512 + cp] : 0.0f;
            float w20 = (rqok && cmok) ? img[(size_t)rq * 512 + cm] : 0.0f;
            float w21 = rqok ? img[(size_t)rq * 512 + pc] : 0.0f;
            float w22 = (rqok && cpok) ? img[(size_t)rq * 512 + cp] : 0.0f;

            // Bit-exact replication of the fast path (same op forms/values)
            float gxf = fmaf(2.0f, w10, w00 + w20) - fmaf(2.0f, w12, w02 + w22);
            float gyf = fmaf(2.0f, w01 - w21, (w00 - w20) + (w02 - w22));
            float magf = __builtin_amdgcn_sqrtf(fmaf(gxf, gxf, gyf * gyf));
            int negf = (int)(__float_as_uint(fmaf(fabsf(gxf), 0.95105651629515353f, -(fabsf(gyf) * 0.30901699437494740f))) >> 31)
                     + (int)(__float_as_uint(fmaf(fabsf(gxf), 0.80901699437494745f, -(fabsf(gyf) * 0.58778525229247314f))) >> 31)
                     + (int)(__float_as_uint(fmaf(fabsf(gxf), 0.58778525229247314f, -(fabsf(gyf) * 0.80901699437494745f))) >> 31)
                     + (int)(__float_as_uint(fmaf(fabsf(gxf), 0.30901699437494740f, -(fabsf(gyf) * 0.95105651629515353f))) >> 31);
            bool qqf = (((__float_as_uint(gxf) ^ __float_as_uint(gyf)) >> 31) != 0u);
            int onesf = 4 - negf;   // fast path added to side[qqf], j=0..onesf

            // Undo fast contribution (cumulative coordinates)
            float uv = -(magf + KFOLD);
#pragma unroll
            for (int j = 0; j < 5; ++j) {
                acc[j].x += (!qqf && j <= onesf) ? uv : 0.0f;
                acc[j].y += ( qqf && j <= onesf) ? uv : 0.0f;
            }

            // Exact f64 sector classification (no atan2).
            double gxd = (((((double)w00 - (double)w02) + 2.0 * (double)w10)
                           - 2.0 * (double)w12) + (double)w20) - (double)w22;
            double gyd = (((((double)w00 + 2.0 * (double)w01) + (double)w02)
                           - (double)w20) - 2.0 * (double)w21) - (double)w22;
            bool sideB;
            int onese;
            float mvals;
            if (gxd == 0.0) {        // p = 0 / +-10 -> bin 0 (A side, s=0)
                sideB = false; onese = 0; mvals = 1.0f;
            } else if (gyd == 0.0) { // p = +-5 -> bin 5 (B side, s=4)
                sideB = true; onese = 4; mvals = 1.0f;
            } else {
                double ad = fabs(gxd), bd = fabs(gyd);
                double M1 = fma(ad, 0.95105651629515353118, -(bd * 0.30901699437494742410));
                double M2 = fma(ad, 0.80901699437494742410, -(bd * 0.58778525229247312917));
                double M3 = fma(ad, 0.58778525229247312917, -(bd * 0.80901699437494742410));
                double M4 = fma(ad, 0.30901699437494742410, -(bd * 0.95105651629515353118));
                int negd = (int)(M1 < 0.0) + (int)(M2 < 0.0)
                         + (int)(M3 < 0.0) + (int)(M4 < 0.0);
                sideB = (gxd < 0.0) != (gyd < 0.0);
                onese = 4 - negd;
                mvals = magf;
            }
            float av = mvals + KFOLD;
#pragma unroll
            for (int j = 0; j < 5; ++j) {
                acc[j].x += (!sideB && j <= onese) ? av : 0.0f;
                acc[j].y += ( sideB && j <= onese) ? av : 0.0f;
            }
        }
    }

    // ---- Tail: unfold counts, telescope, combine, reduce, store ----
    float Am[5], An[5], Bm[5], Bn[5];
#pragma unroll
    for (int j = 0; j < 5; ++j) {
        float qa = rintf(acc[j].x * KFOLD_INV);
        Am[j] = fmaf(qa, -KFOLD, acc[j].x);
        An[j] = qa;
        float qb = rintf(acc[j].y * KFOLD_INV);
        Bm[j] = fmaf(qb, -KFOLD, acc[j].y);
        Bn[j] = qb;
    }
    float M[10], C[10];
#pragma unroll
    for (int sdx = 0; sdx < 5; ++sdx) {
        float am1 = (sdx < 4) ? Am[sdx + 1] : 0.0f;
        float an1 = (sdx < 4) ? An[sdx + 1] : 0.0f;
        M[sdx] = Am[sdx] - am1;             // bin s (A side), s = #ones
        C[sdx] = An[sdx] - an1;
        float bm1 = (sdx < 4) ? Bm[sdx + 1] : 0.0f;
        float bn1 = (sdx < 4) ? Bn[sdx + 1] : 0.0f;
        M[9 - sdx] = Bm[sdx] - bm1;         // bin 9-s (B side)
        C[9 - sdx] = Bn[sdx] - bn1;
    }

    float* op = out + (((size_t)n * 10) * 64 + ch) * 64 + cw;
#pragma unroll
    for (int b = 0; b < 10; ++b) {
        int bm1 = (b + 9) % 10;
        float v = (M[b] - M[bm1]) + C[bm1];
        v += __shfl_xor(v, 1);
        v += __shfl_xor(v, 2);
        v += __shfl_xor(v, 4);
        if (r == 0) op[(size_t)b * 4096] = v * (1.0f / 64.0f);
    }
}

extern "C" void kernel_launch(void* const* d_in, const int* in_sizes, int n_in,
                              void* d_out, int out_size, void* d_ws, size_t ws_size,
                              hipStream_t stream) {
    const float* x = (const float*)d_in[0];
    float* out = (float*)d_out;
    // 1024 blocks (16 images x 64 cell-rows) x 512 threads (8 per cell)
    hog_kernel<<<16 * 64, 512, 0, stream>>>(x, out);
}

// Round 17
// 15.072 us; speedup vs baseline: 1.0966x; 1.0966x over previous
//
#include <hip/hip_runtime.h>
#include <math.h>

// sin(3e-5 * pi/10): proven in r15 (absmax unchanged vs the 3e-4 rounds).
#define THR_BASE 9.42477e-6f
#define KFOLD 256.0f          // count-fold constant: acc += mag + KFOLD
#define KFOLD_INV 0.00390625f // 1/256
#define LSTRIDE 532           // dwords/LDS row (16B-aligned rows)

typedef float v2f __attribute__((ext_vector_type(2)));

// x: (16,1,512,512) f32 ; out: (16,10,64,64) f32
// Block (256 thr) = one cell-row (ch, n uniform). 4 threads/cell, 16 px.
// r15-proven structure + pk sector tests + 3xb128 halo + uniform-stage path.
__global__ void __launch_bounds__(256) hog_kernel(const float* __restrict__ x,
                                                  float* __restrict__ out) {
    __shared__ float s[10 * LSTRIDE];

    int tid = threadIdx.x;
    int blk = blockIdx.x;
    int ch  = blk & 63;          // block-uniform cell-row
    int n   = blk >> 6;          // block-uniform image
    const float* img = x + (size_t)n * (512 * 512);
    int R0 = ch * 8 - 1;         // first staged image row

    // ---- Stage: 10 rows x 512 cols (1280 float4, 5/thread), coalesced.
    if (R0 >= 0 && R0 + 9 < 512) {          // interior cell-row (1008/1024)
#pragma unroll
        for (int k = 0; k < 5; ++k) {
            int j = tid + k * 256;           // 0..1279
            int lrow = j >> 7;               // 128 float4 per row
            int cb = j & 127;
            const float4* gp = (const float4*)(img + (size_t)(R0 + lrow) * 512) + cb;
            float4 v = *gp;
            int L = lrow * LSTRIDE + 5 + cb * 4;
            s[L + 0] = v.x; s[L + 1] = v.y; s[L + 2] = v.z; s[L + 3] = v.w;
        }
    } else {                                 // ch = 0 / 63: row predication
#pragma unroll
        for (int k = 0; k < 5; ++k) {
            int j = tid + k * 256;
            int lrow = j >> 7;
            int cb = j & 127;
            int R = R0 + lrow;
            bool rok = (R >= 0) && (R < 512);
            const float4* gp = (const float4*)(img + (size_t)(rok ? R : 0) * 512) + cb;
            float4 v = *gp;
            float m = rok ? 1.0f : 0.0f;     // zero out-of-range rows
            int L = lrow * LSTRIDE + 5 + cb * 4;
            s[L + 0] = v.x * m; s[L + 1] = v.y * m;
            s[L + 2] = v.z * m; s[L + 3] = v.w * m;
        }
    }
    if (tid < 10) {                          // zero pads: img col -1 and 512
        s[tid * LSTRIDE + 4]   = 0.0f;
        s[tid * LSTRIDE + 517] = 0.0f;
    }
    __syncthreads();

    int r2   = tid & 3;          // row-pair within cell
    int cw   = tid >> 2;         // cell within the block's row (0..63)
    int row0 = ch * 8 + r2 * 2;  // first of this thread's 2 pixel rows
    int col0 = cw * 8;

    // ---- Halo read from LDS: 4 rows x 10 cols via 3x ds_read_b128 each.
    float t0[10], t1[10], t2[10], t3[10];
    {
        int base = (2 * r2) * LSTRIDE + 8 * cw + 4;
#define READROW(DST, D)                                                   \
        {                                                                 \
            const float* rp = &s[base + (D) * LSTRIDE];                   \
            float4 a4 = *(const float4*)(rp);                             \
            float4 b4 = *(const float4*)(rp + 4);                         \
            float4 c4 = *(const float4*)(rp + 8);                         \
            DST[0] = a4.x; DST[1] = a4.y; DST[2] = a4.z; DST[3] = a4.w;   \
            DST[4] = b4.x; DST[5] = b4.y; DST[6] = b4.z; DST[7] = b4.w;   \
            DST[8] = c4.x; DST[9] = c4.y;                                 \
        }
        READROW(t0, 0)
        READROW(t1, 1)
        READROW(t2, 2)
        READROW(t3, 3)
#undef READROW
    }

    // ---- dd (col sums) / uu (row diffs) per pixel row ----
    float dd0[10], dd1[10], uu0[10], uu1[10];
#pragma unroll
    for (int c = 0; c < 10; ++c) {
        dd0[c] = fmaf(2.0f, t1[c], t0[c] + t2[c]);  // pixel row row0
        dd1[c] = fmaf(2.0f, t2[c], t1[c] + t3[c]);  // pixel row row0+1
        uu0[c] = t0[c] - t2[c];
        uu1[c] = t1[c] - t3[c];
    }

    // ---- all 16 gx / gy ----
    float gx[16], gy[16];
#pragma unroll
    for (int c = 0; c < 8; ++c) {
        gx[c]     = dd0[c] - dd0[c + 2];
        gx[8 + c] = dd1[c] - dd1[c + 2];
        gy[c]     = fmaf(2.0f, uu0[c + 1], uu0[c] + uu0[c + 2]);
        gy[8 + c] = fmaf(2.0f, uu1[c + 1], uu1[c] + uu1[c + 2]);
    }

    // Packed sector-test constants: (cos k, cos k+1) / (sin k, sin k+1)
    const v2f C12 = {0.95105651629515353f, 0.80901699437494745f};
    const v2f C34 = {0.58778525229247314f, 0.30901699437494740f};
    const v2f S12 = {0.30901699437494740f, 0.58778525229247314f};
    const v2f S34 = {0.80901699437494745f, 0.95105651629515353f};

    // ---- hot loop: packed cumulative-threshold accumulate ----
    v2f acc[5];                     // .x = A side (qq=0), .y = B side (qq=1)
#pragma unroll
    for (int j = 0; j < 5; ++j) acc[j] = (v2f)(0.0f);
    unsigned bmask = 0u;            // boundary-pixel flags (rare), 16 bits

#pragma unroll
    for (int p = 0; p < 16; ++p) {
        float gxc = gx[p], gyc = gy[p];
        float mag = __builtin_amdgcn_sqrtf(fmaf(gxc, gxc, gyc * gyc));
        float a = fabsf(gxc), b = fabsf(gyc);

        // Sector tests (v_pk_mul/v_pk_fma): m_k = a*cos_k - b*sin_k, k=1..4.
        // IEEE-identical per half to scalar fmaf(a, c_k, -(b*s_k)).
        v2f av; av.x = a; av.y = a;
        v2f bv; bv.x = b; bv.y = b;
        v2f m12 = __builtin_elementwise_fma(av, C12, -(bv * S12));
        v2f m34 = __builtin_elementwise_fma(av, C34, -(bv * S34));
        float m1 = m12.x, m2 = m12.y, m3 = m34.x, m4 = m34.y;

        int k1 = __float_as_int(m1) >> 31;   // all-ones iff m_k < 0
        int k2 = __float_as_int(m2) >> 31;
        int k3 = __float_as_int(m3) >> 31;
        int k4 = __float_as_int(m4) >> 31;
        int qm = (__float_as_int(gxc) ^ __float_as_int(gyc)) >> 31; // qq mask

        int fK = __float_as_int(mag + KFOLD);
        int fA = fK & ~qm;                   // magK on A side, else 0
        int fB = fK & qm;                    // magK on B side, else 0

        v2f v0; v0.x = __int_as_float(fA);      v0.y = __int_as_float(fB);
        v2f v1; v1.x = __int_as_float(fA & ~k1); v1.y = __int_as_float(fB & ~k1);
        v2f v2; v2.x = __int_as_float(fA & ~k2); v2.y = __int_as_float(fB & ~k2);
        v2f v3; v3.x = __int_as_float(fA & ~k3); v3.y = __int_as_float(fB & ~k3);
        v2f v4; v4.x = __int_as_float(fA & ~k4); v4.y = __int_as_float(fB & ~k4);
        acc[0] += v0; acc[1] += v1; acc[2] += v2; acc[3] += v3; acc[4] += v4;

        float dmin = fminf(fminf(fminf(fabsf(m1), fabsf(m2)), fabsf(m3)),
                           fminf(fminf(fabsf(m4), a), b));
        bmask = (dmin < THR_BASE * fmaxf(mag, 1.0f)) ? (bmask | (1u << p)) : bmask;
    }

    // ---- Rare fixup: undo fast contribution, apply exact f64 sector ----
    while (__any((int)(bmask != 0u))) {
        if (bmask) {
            int p = (int)__builtin_ctz(bmask);
            bmask &= bmask - 1u;
            int prow = row0 + (p >> 3);
            int pc   = col0 + (p & 7);
            int rm = prow - 1, rq = prow + 1;
            int cm = pc - 1, cp = pc + 1;
            bool rmok = rm >= 0, rqok = rq < 512;
            bool cmok = cm >= 0, cpok = cp < 512;
            float w00 = (rmok && cmok) ? img[(size_t)rm * 512 + cm] : 0.0f;
            float w01 = rmok ? img[(size_t)rm * 512 + pc] : 0.0f;
            float w02 = (rmok && cpok) ? img[(size_t)rm * 512 + cp] : 0.0f;
            float w10 = cmok ? img[(size_t)prow * 512 + cm] : 0.0f;
            float w12 = cpok ? img[(size_t)prow * 512 + cp] : 0.0f;
            float w20 = (rqok && cmok) ? img[(size_t)rq * 512 + cm] : 0.0f;
            float w21 = rqok ? img[(size_t)rq * 512 + pc] : 0.0f;
            float w22 = (rqok && cpok) ? img[(size_t)rq * 512 + cp] : 0.0f;

            // Bit-exact replication of the fast path (same op forms/values)
            float gxf = fmaf(2.0f, w10, w00 + w20) - fmaf(2.0f, w12, w02 + w22);
            float gyf = fmaf(2.0f, w01 - w21, (w00 - w20) + (w02 - w22));
            float magf = __builtin_amdgcn_sqrtf(fmaf(gxf, gxf, gyf * gyf));
            int negf = (int)(__float_as_uint(fmaf(fabsf(gxf), 0.95105651629515353f, -(fabsf(gyf) * 0.30901699437494740f))) >> 31)
                     + (int)(__float_as_uint(fmaf(fabsf(gxf), 0.80901699437494745f, -(fabsf(gyf) * 0.58778525229247314f))) >> 31)
                     + (int)(__float_as_uint(fmaf(fabsf(gxf), 0.58778525229247314f, -(fabsf(gyf) * 0.80901699437494745f))) >> 31)
                     + (int)(__float_as_uint(fmaf(fabsf(gxf), 0.30901699437494740f, -(fabsf(gyf) * 0.95105651629515353f))) >> 31);
            bool qqf = (((__float_as_uint(gxf) ^ __float_as_uint(gyf)) >> 31) != 0u);
            int onesf = 4 - negf;   // fast path added to side[qqf], j=0..onesf

            // Undo fast contribution (cumulative coordinates)
            float uv = -(magf + KFOLD);
#pragma unroll
            for (int j = 0; j < 5; ++j) {
                acc[j].x += (!qqf && j <= onesf) ? uv : 0.0f;
                acc[j].y += ( qqf && j <= onesf) ? uv : 0.0f;
            }

            // Exact f64 sector classification (no atan2).
            double gxd = (((((double)w00 - (double)w02) + 2.0 * (double)w10)
                           - 2.0 * (double)w12) + (double)w20) - (double)w22;
            double gyd = (((((double)w00 + 2.0 * (double)w01) + (double)w02)
                           - (double)w20) - 2.0 * (double)w21) - (double)w22;
            bool sideB;
            int onese;
            float mvals;
            if (gxd == 0.0) {        // p = 0 / +-10 -> bin 0 (A side, s=0)
                sideB = false; onese = 0; mvals = 1.0f;
            } else if (gyd == 0.0) { // p = +-5 -> bin 5 (B side, s=4)
                sideB = true; onese = 4; mvals = 1.0f;
            } else {
                double ad = fabs(gxd), bd = fabs(gyd);
                double M1 = fma(ad, 0.95105651629515353118, -(bd * 0.30901699437494742410));
                double M2 = fma(ad, 0.80901699437494742410, -(bd * 0.58778525229247312917));
                double M3 = fma(ad, 0.58778525229247312917, -(bd * 0.80901699437494742410));
                double M4 = fma(ad, 0.30901699437494742410, -(bd * 0.95105651629515353118));
                int negd = (int)(M1 < 0.0) + (int)(M2 < 0.0)
                         + (int)(M3 < 0.0) + (int)(M4 < 0.0);
                sideB = (gxd < 0.0) != (gyd < 0.0);
                onese = 4 - negd;
                mvals = magf;
            }
            float av2 = mvals + KFOLD;
#pragma unroll
            for (int j = 0; j < 5; ++j) {
                acc[j].x += (!sideB && j <= onese) ? av2 : 0.0f;
                acc[j].y += ( sideB && j <= onese) ? av2 : 0.0f;
            }
        }
    }

    // ---- Tail: unfold counts, telescope, combine, reduce, store ----
    float Am[5], An[5], Bm[5], Bn[5];
#pragma unroll
    for (int j = 0; j < 5; ++j) {
        float qa = rintf(acc[j].x * KFOLD_INV);
        Am[j] = fmaf(qa, -KFOLD, acc[j].x);
        An[j] = qa;
        float qb = rintf(acc[j].y * KFOLD_INV);
        Bm[j] = fmaf(qb, -KFOLD, acc[j].y);
        Bn[j] = qb;
    }
    float M[10], C[10];
#pragma unroll
    for (int sdx = 0; sdx < 5; ++sdx) {
        float am1 = (sdx < 4) ? Am[sdx + 1] : 0.0f;
        float an1 = (sdx < 4) ? An[sdx + 1] : 0.0f;
        M[sdx] = Am[sdx] - am1;             // bin s (A side), s = #ones
        C[sdx] = An[sdx] - an1;
        float bm1 = (sdx < 4) ? Bm[sdx + 1] : 0.0f;
        float bn1 = (sdx < 4) ? Bn[sdx + 1] : 0.0f;
        M[9 - sdx] = Bm[sdx] - bm1;         // bin 9-s (B side)
        C[9 - sdx] = Bn[sdx] - bn1;
    }

    float* op = out + (((size_t)n * 10) * 64 + ch) * 64 + cw;
#pragma unroll
    for (int b = 0; b < 10; ++b) {
        int bm1 = (b + 9) % 10;
        float v = (M[b] - M[bm1]) + C[bm1];
        v += __shfl_xor(v, 1);
        v += __shfl_xor(v, 2);
        if (r2 == 0) op[(size_t)b * 4096] = v * (1.0f / 64.0f);
    }
}

extern "C" void kernel_launch(void* const* d_in, const int* in_sizes, int n_in,
                              void* d_out, int out_size, void* d_ws, size_t ws_size,
                              hipStream_t stream) {
    const float* x = (const float*)d_in[0];
    float* out = (float*)d_out;
    // 1024 blocks (16 images x 64 cell-rows) x 256 threads (4 per cell)
    hog_kernel<<<16 * 64, 256, 0, stream>>>(x, out);
}